// Round 6
// baseline (455.288 us; speedup 1.0000x reference)
//
#include <hip/hip_runtime.h>

#define NN 50000
#define D 128
#define EE 600000
#define R 8
#define NR (NN * R)            /* segments, key = dst*R + rel (node-major) */
#define NCHUNK 36              /* 1152 / 32 k-chunks */
#define SCAN_CHUNK 1024
#define NSB ((NR + SCAN_CHUNK - 1) / SCAN_CHUNK) /* 391 */

typedef unsigned short u16;
typedef unsigned int u32;
typedef __attribute__((ext_vector_type(8))) short bf16x8;
typedef __attribute__((ext_vector_type(4))) float f32x4;

__device__ inline u16 f2bf(float f) {
    union { float f; u32 u; } v; v.f = f;
    return (u16)((v.u + 0x7FFFu + ((v.u >> 16) & 1u)) >> 16);
}
__device__ inline float bf2f(u16 h) {
    union { u32 u; float f; } v; v.u = ((u32)h) << 16;
    return v.f;
}

// ---- cast x fp32 -> packed bf16 pairs ----
__global__ __launch_bounds__(256) void xcast_kernel(const float2* __restrict__ x2,
                                                    u32* __restrict__ xb, int n) {
    int i = blockIdx.x * 256 + threadIdx.x;
    if (i < n) {
        float2 v = x2[i];
        xb[i] = (u32)f2bf(v.x) | ((u32)f2bf(v.y) << 16);
    }
}

// ---- histogram per segment key = dst*R + rel ----
__global__ __launch_bounds__(256) void hist_kernel(const int* __restrict__ dst,
                                                   const int* __restrict__ et,
                                                   int* __restrict__ cnt, int E) {
    int e = blockIdx.x * 256 + threadIdx.x;
    if (e < E) atomicAdd(&cnt[dst[e] * R + et[e]], 1);
}

// ---- exclusive scan, 3-pass ----
__global__ __launch_bounds__(256) void scanA(const int* __restrict__ cnt,
                                             int* __restrict__ off,
                                             int* __restrict__ bsum) {
    __shared__ int ts[256];
    const int b = blockIdx.x, t = threadIdx.x;
    const int base = b * SCAN_CHUNK + t * 4;
    int v0 = 0, v1 = 0, v2 = 0, v3 = 0;
    if (base + 3 < NR) {
        int4 q = *(const int4*)(cnt + base);
        v0 = q.x; v1 = q.y; v2 = q.z; v3 = q.w;
    } else {
        if (base < NR) v0 = cnt[base];
        if (base + 1 < NR) v1 = cnt[base + 1];
        if (base + 2 < NR) v2 = cnt[base + 2];
    }
    const int s = v0 + v1 + v2 + v3;
    ts[t] = s;
    __syncthreads();
    for (int d = 1; d < 256; d <<= 1) {
        int x = (t >= d) ? ts[t - d] : 0;
        __syncthreads();
        ts[t] += x;
        __syncthreads();
    }
    const int excl = ts[t] - s;
    if (base < NR) off[base] = excl;
    if (base + 1 < NR) off[base + 1] = excl + v0;
    if (base + 2 < NR) off[base + 2] = excl + v0 + v1;
    if (base + 3 < NR) off[base + 3] = excl + v0 + v1 + v2;
    if (t == 255) bsum[b] = ts[255];
}

__global__ __launch_bounds__(512) void scanB(const int* __restrict__ bsum,
                                             int* __restrict__ boff) {
    __shared__ int ts[512];
    const int t = threadIdx.x;
    const int v = (t < NSB) ? bsum[t] : 0;
    ts[t] = v;
    __syncthreads();
    for (int d = 1; d < 512; d <<= 1) {
        int x = (t >= d) ? ts[t - d] : 0;
        __syncthreads();
        ts[t] += x;
        __syncthreads();
    }
    if (t < NSB) boff[t] = ts[t] - v;
}

// adds block offsets; writes BOTH off and cursor (saves a d2d copy)
__global__ __launch_bounds__(256) void scanC(int* __restrict__ off,
                                             int* __restrict__ cursor,
                                             const int* __restrict__ boff) {
    const int b = blockIdx.x, t = threadIdx.x;
    const int add = boff[b];
    const int base = b * SCAN_CHUNK + t * 4;
#pragma unroll
    for (int j = 0; j < 4; ++j)
        if (base + j < NR) {
            int v = off[base + j] + add;
            off[base + j] = v;
            cursor[base + j] = v;
        }
    if (b == 0 && t == 0) off[NR] = EE;
}

// ---- place edge sources into segment-sorted order ----
__global__ __launch_bounds__(256) void place_kernel(const int* __restrict__ src,
                                                    const int* __restrict__ dst,
                                                    const int* __restrict__ et,
                                                    int* __restrict__ cursor,
                                                    int* __restrict__ ss, int E) {
    int e = blockIdx.x * 256 + threadIdx.x;
    if (e < E) {
        int key = dst[e] * R + et[e];
        int p = atomicAdd(&cursor[key], 1);
        ss[p] = src[e];
    }
}

// ---- pack both layers' B = [w;root] into bf16 MFMA B-fragment order ----
__global__ __launch_bounds__(256) void bprep2_kernel(const float* __restrict__ w1,
                                                     const float* __restrict__ root1,
                                                     u16* __restrict__ Bf1,
                                                     const float* __restrict__ w2,
                                                     const float* __restrict__ root2,
                                                     u16* __restrict__ Bf2) {
    int gidx = blockIdx.x * 256 + threadIdx.x;  // over 2*36*8*64 = 36864
    if (gidx >= 2 * NCHUNK * 8 * 64) return;
    const int layer = gidx / (NCHUNK * 8 * 64);
    const int idx = gidx - layer * (NCHUNK * 8 * 64);
    const float* w = layer ? w2 : w1;
    const float* root = layer ? root2 : root1;
    u16* Bfrag = layer ? Bf2 : Bf1;
    int lane = idx & 63;
    int g = (idx >> 6) & 7;
    int kc = idx >> 9;
    int col = g * 16 + (lane & 15);
    int kbase = kc * 32 + (lane >> 4) * 8;
    u16* o = Bfrag + (size_t)idx * 8;
#pragma unroll
    for (int j = 0; j < 8; ++j) {
        int k = kbase + j;
        float v = (k < R * D) ? w[(size_t)k * D + col]
                              : root[(size_t)(k - R * D) * D + col];
        o[j] = f2bf(v);
    }
}

// ---- segment mean: one WAVE per NODE, boundary-walk, no predication ----
// Edges sorted by (node, rel): walk the 8 segments in order with a plain
// accumulator; flush at each (wave-uniform) boundary. Sources come from a
// single lane-parallel load broadcast via __shfl (1 load per 64 edges).
__global__ __launch_bounds__(256) void seg_mean_node(const u32* __restrict__ xb,
                                                     const int* __restrict__ off,
                                                     const int* __restrict__ srcs,
                                                     u32* __restrict__ mean) {
    const int n = blockIdx.x * 4 + (threadIdx.x >> 6);
    const int lane = threadIdx.x & 63;

    int b[9];
#pragma unroll
    for (int r = 0; r <= 8; ++r) b[r] = off[n * 8 + r];
    const int e0 = b[0], e1 = b[8];

    int cbase = e0;
    int sv = (cbase + lane < e1) ? srcs[cbase + lane] : 0;

    int i = e0;
    u32* mout = mean + (size_t)n * (R * D / 2) + lane;
#pragma unroll
    for (int r = 0; r < 8; ++r) {
        const int cnt = b[r + 1] - b[r];
        float ax = 0.f, ay = 0.f;
        for (int k = 0; k < cnt; ++k, ++i) {
            if (i - cbase >= 64) {  // rare: >64 in-edges consumed
                cbase += 64;
                sv = (cbase + lane < e1) ? srcs[cbase + lane] : 0;
            }
            const int s = __shfl(sv, i - cbase);
            const u32 v = xb[(size_t)s * (D / 2) + lane];
            ax += bf2f((u16)(v & 0xFFFFu));
            ay += bf2f((u16)(v >> 16));
        }
        const float inv = (cnt > 0) ? 1.0f / (float)cnt : 0.f;
        mout[r * (D / 2)] = (u32)f2bf(ax * inv) | ((u32)f2bf(ay * inv) << 16);
    }
}

// ---- MFMA GEMM: out[n,:] = relu( [mean(n,:,:), xb(n,:)] @ [w;root] + b ) ----
// Block = 64 nodes, 2 waves; each wave does 32 rows (2 m-frags) x 128 cols,
// so every B-fragment load feeds 2 MFMAs (halves B L2 traffic).
template <bool OUTBF>
__global__ __launch_bounds__(128) void gemm_mfma(const u16* __restrict__ xb,
                                                 const u16* __restrict__ mean,
                                                 const u16* __restrict__ Bfrag,
                                                 const float* __restrict__ bias,
                                                 void* __restrict__ outp) {
    const int t = threadIdx.x;
    const int wave = t >> 6;   // 0..1
    const int lane = t & 63;
    const int quad = lane >> 4;
    const int l15 = lane & 15;
    const int n0 = blockIdx.x * 64;
    const int m0 = n0 + wave * 32 + l15;        // rows m0 and m0+16
    const int nc0 = (m0 < NN) ? m0 : (NN - 1);
    const int nc1 = (m0 + 16 < NN) ? (m0 + 16) : (NN - 1);

    f32x4 acc0[8], acc1[8];
#pragma unroll
    for (int g = 0; g < 8; ++g) {
        acc0[g] = (f32x4){0.f, 0.f, 0.f, 0.f};
        acc1[g] = (f32x4){0.f, 0.f, 0.f, 0.f};
    }

    const u16* bbase = Bfrag + (size_t)lane * 8;
    const u16* arow0 = mean + (size_t)nc0 * (R * D) + quad * 8;
    const u16* arow1 = mean + (size_t)nc1 * (R * D) + quad * 8;

    // relation part: k = 0..1023, bf16 direct from mean (pre-scaled)
#pragma unroll
    for (int kc = 0; kc < 32; ++kc) {
        bf16x8 af0 = *(const bf16x8*)(arow0 + kc * 32);
        bf16x8 af1 = *(const bf16x8*)(arow1 + kc * 32);
#pragma unroll
        for (int g = 0; g < 8; ++g) {
            bf16x8 bf = *(const bf16x8*)(bbase + (size_t)(kc * 8 + g) * 512);
            acc0[g] = __builtin_amdgcn_mfma_f32_16x16x32_bf16(af0, bf, acc0[g], 0, 0, 0);
            acc1[g] = __builtin_amdgcn_mfma_f32_16x16x32_bf16(af1, bf, acc1[g], 0, 0, 0);
        }
    }

    // root part: k = 1024..1151, bf16 from xb
    {
        const u16* xr0 = xb + (size_t)nc0 * D + quad * 8;
        const u16* xr1 = xb + (size_t)nc1 * D + quad * 8;
#pragma unroll
        for (int c = 0; c < 4; ++c) {
            bf16x8 af0 = *(const bf16x8*)(xr0 + c * 32);
            bf16x8 af1 = *(const bf16x8*)(xr1 + c * 32);
            const int kc = 32 + c;
#pragma unroll
            for (int g = 0; g < 8; ++g) {
                bf16x8 bf = *(const bf16x8*)(bbase + (size_t)(kc * 8 + g) * 512);
                acc0[g] = __builtin_amdgcn_mfma_f32_16x16x32_bf16(af0, bf, acc0[g], 0, 0, 0);
                acc1[g] = __builtin_amdgcn_mfma_f32_16x16x32_bf16(af1, bf, acc1[g], 0, 0, 0);
            }
        }
    }

    // epilogue: bias + relu; D mapping: row = quad*4 + q, col = g*16 + l15
#pragma unroll
    for (int g = 0; g < 8; ++g) {
        const int col = g * 16 + l15;
        const float bb = bias[col];
#pragma unroll
        for (int q = 0; q < 4; ++q) {
            const int row0 = n0 + wave * 32 + quad * 4 + q;
#pragma unroll
            for (int h2 = 0; h2 < 2; ++h2) {
                const int row = row0 + h2 * 16;
                const float a = h2 ? acc1[g][q] : acc0[g][q];
                if (row < NN) {
                    float v = fmaxf(a + bb, 0.f);
                    if (OUTBF)
                        ((u16*)outp)[(size_t)row * D + col] = f2bf(v);
                    else
                        ((float*)outp)[(size_t)row * D + col] = v;
                }
            }
        }
    }
}

extern "C" void kernel_launch(void* const* d_in, const int* in_sizes, int n_in,
                              void* d_out, int out_size, void* d_ws, size_t ws_size,
                              hipStream_t stream) {
    const float* x = (const float*)d_in[0];
    const int* ei = (const int*)d_in[1];
    const int* et = (const int*)d_in[2];
    const float* w1 = (const float*)d_in[3];
    const float* root1 = (const float*)d_in[4];
    const float* b1 = (const float*)d_in[5];
    const float* w2 = (const float*)d_in[6];
    const float* root2 = (const float*)d_in[7];
    const float* b2 = (const float*)d_in[8];
    float* out = (float*)d_out;

    char* ws = (char*)d_ws;
    int* off    = (int*)(ws + 0);                  // (NR+1) ints
    int* cnt_i  = (int*)(ws + 1600512);            // NR ints
    int* cursor = (int*)(ws + 3200512);            // NR ints
    int* bsum   = (int*)(ws + 4800512);            // NSB ints
    int* boff   = (int*)(ws + 4802304);            // NSB ints
    int* srcs   = (int*)(ws + 4804096);            // EE ints (2.4 MB)
    u32* xb     = (u32*)(ws + 7204096);            // N*D bf16 = 12.8 MB
    u32* mean   = (u32*)(ws + 20004096);           // N*R*D bf16 = 102.4 MB
    u32* h      = (u32*)(ws + 122404096);          // N*D bf16 = 12.8 MB
    u16* Bf1    = (u16*)(ws + 135204096);          // 294912 B
    u16* Bf2    = (u16*)(ws + 135499008);          // 294912 B

    const int* srcp = ei;
    const int* dstp = ei + EE;

    // ---- input cast + CSR build (shared by both layers) ----
    xcast_kernel<<<(NN * D / 2 + 255) / 256, 256, 0, stream>>>((const float2*)x,
                                                               xb, NN * D / 2);
    hipMemsetAsync(cnt_i, 0, (size_t)NR * sizeof(int), stream);
    hist_kernel<<<(EE + 255) / 256, 256, 0, stream>>>(dstp, et, cnt_i, EE);
    scanA<<<NSB, 256, 0, stream>>>(cnt_i, off, bsum);
    scanB<<<1, 512, 0, stream>>>(bsum, boff);
    scanC<<<NSB, 256, 0, stream>>>(off, cursor, boff);
    place_kernel<<<(EE + 255) / 256, 256, 0, stream>>>(srcp, dstp, et, cursor,
                                                       srcs, EE);
    bprep2_kernel<<<(2 * NCHUNK * 8 * 64 + 255) / 256, 256, 0, stream>>>(
        w1, root1, Bf1, w2, root2, Bf2);

    const int seg_blocks = NN / 4;            // 12500: one wave per node
    const int gemm_blocks = (NN + 63) / 64;   // 782 (128 threads each)

    // layer 1: xb -> h (bf16)
    seg_mean_node<<<seg_blocks, 256, 0, stream>>>(xb, off, srcs, mean);
    gemm_mfma<true><<<gemm_blocks, 128, 0, stream>>>((const u16*)xb,
                                                     (const u16*)mean, Bf1, b1, h);

    // layer 2: h -> out (fp32)
    seg_mean_node<<<seg_blocks, 256, 0, stream>>>(h, off, srcs, mean);
    gemm_mfma<false><<<gemm_blocks, 128, 0, stream>>>((const u16*)h,
                                                      (const u16*)mean, Bf2, b2, out);
}

// Round 7
// 348.192 us; speedup vs baseline: 1.3076x; 1.3076x over previous
//
#include <hip/hip_runtime.h>

#define NN 50000
#define D 128
#define EE 600000
#define R 8
#define NR (NN * R)            /* segments, key = dst*R + rel (node-major) */
#define NCHUNK 36              /* 1152 / 32 k-chunks */
#define SCAN_CHUNK 1024
#define NSB ((NR + SCAN_CHUNK - 1) / SCAN_CHUNK) /* 391 */

typedef unsigned short u16;
typedef unsigned int u32;
typedef __attribute__((ext_vector_type(8))) short bf16x8;
typedef __attribute__((ext_vector_type(4))) float f32x4;

__device__ inline u16 f2bf(float f) {
    union { float f; u32 u; } v; v.f = f;
    return (u16)((v.u + 0x7FFFu + ((v.u >> 16) & 1u)) >> 16);
}
__device__ inline float bf2f(u16 h) {
    union { u32 u; float f; } v; v.u = ((u32)h) << 16;
    return v.f;
}

// ---- cast x fp32 -> packed bf16 pairs ----
__global__ __launch_bounds__(256) void xcast_kernel(const float2* __restrict__ x2,
                                                    u32* __restrict__ xb, int n) {
    int i = blockIdx.x * 256 + threadIdx.x;
    if (i < n) {
        float2 v = x2[i];
        xb[i] = (u32)f2bf(v.x) | ((u32)f2bf(v.y) << 16);
    }
}

// ---- histogram per segment key = dst*R + rel ----
__global__ __launch_bounds__(256) void hist_kernel(const int* __restrict__ dst,
                                                   const int* __restrict__ et,
                                                   int* __restrict__ cnt, int E) {
    int e = blockIdx.x * 256 + threadIdx.x;
    if (e < E) atomicAdd(&cnt[dst[e] * R + et[e]], 1);
}

// ---- exclusive scan, 3-pass ----
__global__ __launch_bounds__(256) void scanA(const int* __restrict__ cnt,
                                             int* __restrict__ off,
                                             int* __restrict__ bsum) {
    __shared__ int ts[256];
    const int b = blockIdx.x, t = threadIdx.x;
    const int base = b * SCAN_CHUNK + t * 4;
    int v0 = 0, v1 = 0, v2 = 0, v3 = 0;
    if (base + 3 < NR) {
        int4 q = *(const int4*)(cnt + base);
        v0 = q.x; v1 = q.y; v2 = q.z; v3 = q.w;
    } else {
        if (base < NR) v0 = cnt[base];
        if (base + 1 < NR) v1 = cnt[base + 1];
        if (base + 2 < NR) v2 = cnt[base + 2];
    }
    const int s = v0 + v1 + v2 + v3;
    ts[t] = s;
    __syncthreads();
    for (int d = 1; d < 256; d <<= 1) {
        int x = (t >= d) ? ts[t - d] : 0;
        __syncthreads();
        ts[t] += x;
        __syncthreads();
    }
    const int excl = ts[t] - s;
    if (base < NR) off[base] = excl;
    if (base + 1 < NR) off[base + 1] = excl + v0;
    if (base + 2 < NR) off[base + 2] = excl + v0 + v1;
    if (base + 3 < NR) off[base + 3] = excl + v0 + v1 + v2;
    if (t == 255) bsum[b] = ts[255];
}

__global__ __launch_bounds__(512) void scanB(const int* __restrict__ bsum,
                                             int* __restrict__ boff) {
    __shared__ int ts[512];
    const int t = threadIdx.x;
    const int v = (t < NSB) ? bsum[t] : 0;
    ts[t] = v;
    __syncthreads();
    for (int d = 1; d < 512; d <<= 1) {
        int x = (t >= d) ? ts[t - d] : 0;
        __syncthreads();
        ts[t] += x;
        __syncthreads();
    }
    if (t < NSB) boff[t] = ts[t] - v;
}

// adds block offsets; writes BOTH off and cursor (saves a d2d copy)
__global__ __launch_bounds__(256) void scanC(int* __restrict__ off,
                                             int* __restrict__ cursor,
                                             const int* __restrict__ boff) {
    const int b = blockIdx.x, t = threadIdx.x;
    const int add = boff[b];
    const int base = b * SCAN_CHUNK + t * 4;
#pragma unroll
    for (int j = 0; j < 4; ++j)
        if (base + j < NR) {
            int v = off[base + j] + add;
            off[base + j] = v;
            cursor[base + j] = v;
        }
    if (b == 0 && t == 0) off[NR] = EE;
}

// ---- place edge sources into segment-sorted order ----
__global__ __launch_bounds__(256) void place_kernel(const int* __restrict__ src,
                                                    const int* __restrict__ dst,
                                                    const int* __restrict__ et,
                                                    int* __restrict__ cursor,
                                                    int* __restrict__ ss, int E) {
    int e = blockIdx.x * 256 + threadIdx.x;
    if (e < E) {
        int key = dst[e] * R + et[e];
        int p = atomicAdd(&cursor[key], 1);
        ss[p] = src[e];
    }
}

// ---- pack both layers' B = [w;root] into bf16 MFMA B-fragment order ----
__global__ __launch_bounds__(256) void bprep2_kernel(const float* __restrict__ w1,
                                                     const float* __restrict__ root1,
                                                     u16* __restrict__ Bf1,
                                                     const float* __restrict__ w2,
                                                     const float* __restrict__ root2,
                                                     u16* __restrict__ Bf2) {
    int gidx = blockIdx.x * 256 + threadIdx.x;  // over 2*36*8*64 = 36864
    if (gidx >= 2 * NCHUNK * 8 * 64) return;
    const int layer = gidx / (NCHUNK * 8 * 64);
    const int idx = gidx - layer * (NCHUNK * 8 * 64);
    const float* w = layer ? w2 : w1;
    const float* root = layer ? root2 : root1;
    u16* Bfrag = layer ? Bf2 : Bf1;
    int lane = idx & 63;
    int g = (idx >> 6) & 7;
    int kc = idx >> 9;
    int col = g * 16 + (lane & 15);
    int kbase = kc * 32 + (lane >> 4) * 8;
    u16* o = Bfrag + (size_t)idx * 8;
#pragma unroll
    for (int j = 0; j < 8; ++j) {
        int k = kbase + j;
        float v = (k < R * D) ? w[(size_t)k * D + col]
                              : root[(size_t)(k - R * D) * D + col];
        o[j] = f2bf(v);
    }
}

// ---- segment mean: one WAVE per NODE, boundary-walk ----
__global__ __launch_bounds__(256) void seg_mean_node(const u32* __restrict__ xb,
                                                     const int* __restrict__ off,
                                                     const int* __restrict__ srcs,
                                                     u32* __restrict__ mean) {
    const int n = blockIdx.x * 4 + (threadIdx.x >> 6);
    const int lane = threadIdx.x & 63;

    int b[9];
#pragma unroll
    for (int r = 0; r <= 8; ++r) b[r] = off[n * 8 + r];
    const int e0 = b[0], e1 = b[8];

    int cbase = e0;
    int sv = (cbase + lane < e1) ? srcs[cbase + lane] : 0;

    int i = e0;
    u32* mout = mean + (size_t)n * (R * D / 2) + lane;
#pragma unroll
    for (int r = 0; r < 8; ++r) {
        const int cnt = b[r + 1] - b[r];
        float ax = 0.f, ay = 0.f;
        for (int k = 0; k < cnt; ++k, ++i) {
            if (i - cbase >= 64) {  // rare: >64 in-edges consumed
                cbase += 64;
                sv = (cbase + lane < e1) ? srcs[cbase + lane] : 0;
            }
            const int s = __shfl(sv, i - cbase);
            const u32 v = xb[(size_t)s * (D / 2) + lane];
            ax += bf2f((u16)(v & 0xFFFFu));
            ay += bf2f((u16)(v >> 16));
        }
        const float inv = (cnt > 0) ? 1.0f / (float)cnt : 0.f;
        mout[r * (D / 2)] = (u32)f2bf(ax * inv) | ((u32)f2bf(ay * inv) << 16);
    }
}

// ---- MFMA GEMM: out[n,:] = relu( [mean(n,:,:), xb(n,:)] @ [w;root] + b ) ----
// 256 threads, 64 rows/block (16 rows/wave). B k-chunk (8 KB) staged in LDS
// once per block and shared by all 4 waves (4x less L2 B traffic than
// per-wave loads). Software-pipelined: next chunk's global loads + next A
// fragment issued right after the barrier, compute current from LDS.
template <bool OUTBF>
__global__ __launch_bounds__(256) void gemm_mfma(const u16* __restrict__ xb,
                                                 const u16* __restrict__ mean,
                                                 const u16* __restrict__ Bfrag,
                                                 const float* __restrict__ bias,
                                                 void* __restrict__ outp) {
    __shared__ uint4 Bs[512];  // 8 frags x 64 lanes x 16 B = 8 KB

    const int t = threadIdx.x;
    const int wave = t >> 6;
    const int lane = t & 63;
    const int quad = lane >> 4;
    const int l15 = lane & 15;
    const int n0 = blockIdx.x * 64;
    const int n = n0 + wave * 16 + l15;
    const int nc = (n < NN) ? n : (NN - 1);  // clamp loads; stores guarded

    f32x4 acc[8];
#pragma unroll
    for (int g = 0; g < 8; ++g) acc[g] = (f32x4){0.f, 0.f, 0.f, 0.f};

    const u16* arow = mean + (size_t)nc * (R * D) + quad * 8;  // + kc*32
    const u16* xrow = xb + (size_t)nc * D + quad * 8;          // + (kc-32)*32

    // preload stage 0
    const uint4* gsrc = (const uint4*)Bfrag;  // chunk kc at gsrc + kc*512
    uint4 bv0 = gsrc[t];
    uint4 bv1 = gsrc[t + 256];
    bf16x8 af = *(const bf16x8*)(arow);  // kc = 0

#pragma unroll 1
    for (int kc = 0; kc < NCHUNK; ++kc) {
        __syncthreads();  // previous-stage LDS reads complete
        Bs[t] = bv0;
        Bs[t + 256] = bv1;
        __syncthreads();  // stage visible

        const bf16x8 afc = af;
        if (kc + 1 < NCHUNK) {  // issue next-stage loads early
            const uint4* gn = gsrc + (size_t)(kc + 1) * 512;
            bv0 = gn[t];
            bv1 = gn[t + 256];
            af = (kc + 1 < 32) ? *(const bf16x8*)(arow + (kc + 1) * 32)
                               : *(const bf16x8*)(xrow + (kc + 1 - 32) * 32);
        }

        const u16* bb = (const u16*)Bs + lane * 8;
#pragma unroll
        for (int g = 0; g < 8; ++g) {
            bf16x8 bf = *(const bf16x8*)(bb + g * 512);
            acc[g] = __builtin_amdgcn_mfma_f32_16x16x32_bf16(afc, bf, acc[g], 0, 0, 0);
        }
    }

    // epilogue: bias + relu; D mapping: row = quad*4 + q, col = g*16 + l15
#pragma unroll
    for (int g = 0; g < 8; ++g) {
        const int col = g * 16 + l15;
        const float bb = bias[col];
#pragma unroll
        for (int q = 0; q < 4; ++q) {
            const int row = n0 + wave * 16 + quad * 4 + q;
            if (row < NN) {
                float v = fmaxf(acc[g][q] + bb, 0.f);
                if (OUTBF)
                    ((u16*)outp)[(size_t)row * D + col] = f2bf(v);
                else
                    ((float*)outp)[(size_t)row * D + col] = v;
            }
        }
    }
}

extern "C" void kernel_launch(void* const* d_in, const int* in_sizes, int n_in,
                              void* d_out, int out_size, void* d_ws, size_t ws_size,
                              hipStream_t stream) {
    const float* x = (const float*)d_in[0];
    const int* ei = (const int*)d_in[1];
    const int* et = (const int*)d_in[2];
    const float* w1 = (const float*)d_in[3];
    const float* root1 = (const float*)d_in[4];
    const float* b1 = (const float*)d_in[5];
    const float* w2 = (const float*)d_in[6];
    const float* root2 = (const float*)d_in[7];
    const float* b2 = (const float*)d_in[8];
    float* out = (float*)d_out;

    char* ws = (char*)d_ws;
    int* off    = (int*)(ws + 0);                  // (NR+1) ints
    int* cnt_i  = (int*)(ws + 1600512);            // NR ints
    int* cursor = (int*)(ws + 3200512);            // NR ints
    int* bsum   = (int*)(ws + 4800512);            // NSB ints
    int* boff   = (int*)(ws + 4802304);            // NSB ints
    int* srcs   = (int*)(ws + 4804096);            // EE ints (2.4 MB)
    u32* xb     = (u32*)(ws + 7204096);            // N*D bf16 = 12.8 MB
    u32* mean   = (u32*)(ws + 20004096);           // N*R*D bf16 = 102.4 MB
    u32* h      = (u32*)(ws + 122404096);          // N*D bf16 = 12.8 MB
    u16* Bf1    = (u16*)(ws + 135204096);          // 294912 B
    u16* Bf2    = (u16*)(ws + 135499008);          // 294912 B

    const int* srcp = ei;
    const int* dstp = ei + EE;

    // ---- input cast + CSR build (shared by both layers) ----
    xcast_kernel<<<(NN * D / 2 + 255) / 256, 256, 0, stream>>>((const float2*)x,
                                                               xb, NN * D / 2);
    hipMemsetAsync(cnt_i, 0, (size_t)NR * sizeof(int), stream);
    hist_kernel<<<(EE + 255) / 256, 256, 0, stream>>>(dstp, et, cnt_i, EE);
    scanA<<<NSB, 256, 0, stream>>>(cnt_i, off, bsum);
    scanB<<<1, 512, 0, stream>>>(bsum, boff);
    scanC<<<NSB, 256, 0, stream>>>(off, cursor, boff);
    place_kernel<<<(EE + 255) / 256, 256, 0, stream>>>(srcp, dstp, et, cursor,
                                                       srcs, EE);
    bprep2_kernel<<<(2 * NCHUNK * 8 * 64 + 255) / 256, 256, 0, stream>>>(
        w1, root1, Bf1, w2, root2, Bf2);

    const int seg_blocks = NN / 4;            // 12500: one wave per node
    const int gemm_blocks = (NN + 63) / 64;   // 782 (256 threads each)

    // layer 1: xb -> h (bf16)
    seg_mean_node<<<seg_blocks, 256, 0, stream>>>(xb, off, srcs, mean);
    gemm_mfma<true><<<gemm_blocks, 256, 0, stream>>>((const u16*)xb,
                                                     (const u16*)mean, Bf1, b1, h);

    // layer 2: h -> out (fp32)
    seg_mean_node<<<seg_blocks, 256, 0, stream>>>(h, off, srcs, mean);
    gemm_mfma<false><<<gemm_blocks, 256, 0, stream>>>((const u16*)h,
                                                      (const u16*)mean, Bf2, b2, out);
}

// Round 9
// 310.021 us; speedup vs baseline: 1.4686x; 1.1231x over previous
//
#include <hip/hip_runtime.h>

#define NN 50000
#define D 128
#define EE 600000
#define R 8
#define NR (NN * R)            /* segments, key = dst*R + rel (node-major) */
#define SCAN_CHUNK 1024
#define NSB ((NR + SCAN_CHUNK - 1) / SCAN_CHUNK) /* 391 */
#define KO 1152                /* output cols of gemm_xw: 8*128 + 128 */

typedef unsigned short u16;
typedef unsigned int u32;
typedef __attribute__((ext_vector_type(8))) short bf16x8;
typedef __attribute__((ext_vector_type(4))) float f32x4;

__device__ inline u16 f2bf(float f) {
    union { float f; u32 u; } v; v.f = f;
    return (u16)((v.u + 0x7FFFu + ((v.u >> 16) & 1u)) >> 16);
}
__device__ inline float bf2f(u16 h) {
    union { u32 u; float f; } v; v.u = ((u32)h) << 16;
    return v.f;
}

// ---- cast x fp32 -> packed bf16 pairs ----
__global__ __launch_bounds__(256) void xcast_kernel(const float2* __restrict__ x2,
                                                    u32* __restrict__ xb, int n) {
    int i = blockIdx.x * 256 + threadIdx.x;
    if (i < n) {
        float2 v = x2[i];
        xb[i] = (u32)f2bf(v.x) | ((u32)f2bf(v.y) << 16);
    }
}

// ---- histogram per segment key = dst*R + rel ----
__global__ __launch_bounds__(256) void hist_kernel(const int* __restrict__ dst,
                                                   const int* __restrict__ et,
                                                   int* __restrict__ cnt, int E) {
    int e = blockIdx.x * 256 + threadIdx.x;
    if (e < E) atomicAdd(&cnt[dst[e] * R + et[e]], 1);
}

// ---- exclusive scan, 3-pass ----
__global__ __launch_bounds__(256) void scanA(const int* __restrict__ cnt,
                                             int* __restrict__ off,
                                             int* __restrict__ bsum) {
    __shared__ int ts[256];
    const int b = blockIdx.x, t = threadIdx.x;
    const int base = b * SCAN_CHUNK + t * 4;
    int v0 = 0, v1 = 0, v2 = 0, v3 = 0;
    if (base + 3 < NR) {
        int4 q = *(const int4*)(cnt + base);
        v0 = q.x; v1 = q.y; v2 = q.z; v3 = q.w;
    } else {
        if (base < NR) v0 = cnt[base];
        if (base + 1 < NR) v1 = cnt[base + 1];
        if (base + 2 < NR) v2 = cnt[base + 2];
    }
    const int s = v0 + v1 + v2 + v3;
    ts[t] = s;
    __syncthreads();
    for (int d = 1; d < 256; d <<= 1) {
        int x = (t >= d) ? ts[t - d] : 0;
        __syncthreads();
        ts[t] += x;
        __syncthreads();
    }
    const int excl = ts[t] - s;
    if (base < NR) off[base] = excl;
    if (base + 1 < NR) off[base + 1] = excl + v0;
    if (base + 2 < NR) off[base + 2] = excl + v0 + v1;
    if (base + 3 < NR) off[base + 3] = excl + v0 + v1 + v2;
    if (t == 255) bsum[b] = ts[255];
}

__global__ __launch_bounds__(512) void scanB(const int* __restrict__ bsum,
                                             int* __restrict__ boff) {
    __shared__ int ts[512];
    const int t = threadIdx.x;
    const int v = (t < NSB) ? bsum[t] : 0;
    ts[t] = v;
    __syncthreads();
    for (int d = 1; d < 512; d <<= 1) {
        int x = (t >= d) ? ts[t - d] : 0;
        __syncthreads();
        ts[t] += x;
        __syncthreads();
    }
    if (t < NSB) boff[t] = ts[t] - v;
}

// adds block offsets; writes BOTH off and cursor (saves a d2d copy)
__global__ __launch_bounds__(256) void scanC(int* __restrict__ off,
                                             int* __restrict__ cursor,
                                             const int* __restrict__ boff) {
    const int b = blockIdx.x, t = threadIdx.x;
    const int add = boff[b];
    const int base = b * SCAN_CHUNK + t * 4;
#pragma unroll
    for (int j = 0; j < 4; ++j)
        if (base + j < NR) {
            int v = off[base + j] + add;
            off[base + j] = v;
            cursor[base + j] = v;
        }
    if (b == 0 && t == 0) off[NR] = EE;
}

// ---- place: per-edge precomputed gather offset (u32 units of y) + scale ----
__global__ __launch_bounds__(256) void place_kernel(const int* __restrict__ src,
                                                    const int* __restrict__ dst,
                                                    const int* __restrict__ et,
                                                    const int* __restrict__ cnt,
                                                    int* __restrict__ cursor,
                                                    u32* __restrict__ epos,
                                                    float* __restrict__ scale, int E) {
    int e = blockIdx.x * 256 + threadIdx.x;
    if (e < E) {
        int r = et[e];
        int key = dst[e] * R + r;
        int p = atomicAdd(&cursor[key], 1);
        epos[p] = (u32)src[e] * (KO / 2) + (u32)r * (D / 2);
        scale[p] = 1.0f / (float)cnt[key];
    }
}

// ---- pack both layers' B = [W_1..W_8, root] (cols) into MFMA B-frag order ----
// layout: [layer][ct(9)][kc(4)][g(8)][lane(64)][j(8)]
// value = B[k = kc*32 + quad*8 + j][col = ct*128 + g*16 + l15]
__global__ __launch_bounds__(256) void bprep2_kernel(const float* __restrict__ w1,
                                                     const float* __restrict__ root1,
                                                     u16* __restrict__ Bf1,
                                                     const float* __restrict__ w2,
                                                     const float* __restrict__ root2,
                                                     u16* __restrict__ Bf2) {
    int gidx = blockIdx.x * 256 + threadIdx.x;  // over 2*9*4*8*64 = 36864
    if (gidx >= 2 * 9 * 4 * 8 * 64) return;
    const int layer = gidx / (9 * 4 * 8 * 64);
    const int idx = gidx - layer * (9 * 4 * 8 * 64);
    const float* w = layer ? w2 : w1;
    const float* root = layer ? root2 : root1;
    u16* Bfrag = layer ? Bf2 : Bf1;
    const int lane = idx & 63;
    const int g = (idx >> 6) & 7;
    const int kc = (idx >> 9) & 3;
    const int ct = idx >> 11;  // 0..8
    const int col = ct * 128 + g * 16 + (lane & 15);
    const int kbase = kc * 32 + (lane >> 4) * 8;
    u16* o = Bfrag + (size_t)idx * 8;
#pragma unroll
    for (int j = 0; j < 8; ++j) {
        const int k = kbase + j;
        float v = (col < R * D) ? w[(size_t)(col >> 7) * (D * D) + (size_t)k * D + (col & 127)]
                                : root[(size_t)k * D + (col - R * D)];
        o[j] = f2bf(v);
    }
}

// ---- GEMM: y[n, ct*128..] = xin[n,:] @ B-slice  (K=128, bf16 out) ----
// grid (782, 9); 256 thr = 4 waves x 16 rows; B slice = 4 kc x 8 KB = 32 KB
// (2048 uint4) staged in LDS. [Round-8 bug: staged only 16 KB — fixed.]
__global__ __launch_bounds__(256) void gemm_xw(const u16* __restrict__ xin,
                                               const u16* __restrict__ Bfrag,
                                               u16* __restrict__ y) {
    __shared__ uint4 Bs[2048];  // 32 KB

    const int t = threadIdx.x;
    const int wave = t >> 6;
    const int lane = t & 63;
    const int quad = lane >> 4;
    const int l15 = lane & 15;
    const int n0 = blockIdx.x * 64;
    const int ct = blockIdx.y;
    const int n = n0 + wave * 16 + l15;
    const int nc = (n < NN) ? n : (NN - 1);

    // stage this column-tile's B slice (2048 uint4 = 8 per thread)
    const uint4* bsrc = (const uint4*)Bfrag + (size_t)ct * 2048;
    uint4 s[8];
#pragma unroll
    for (int i = 0; i < 8; ++i) s[i] = bsrc[t + 256 * i];

    // A fragments (K = 128 -> 4 chunks), issued before the barrier
    const u16* xr = xin + (size_t)nc * D + quad * 8;
    bf16x8 a0 = *(const bf16x8*)(xr);
    bf16x8 a1 = *(const bf16x8*)(xr + 32);
    bf16x8 a2 = *(const bf16x8*)(xr + 64);
    bf16x8 a3 = *(const bf16x8*)(xr + 96);

#pragma unroll
    for (int i = 0; i < 8; ++i) Bs[t + 256 * i] = s[i];
    __syncthreads();

    f32x4 acc[8];
#pragma unroll
    for (int g = 0; g < 8; ++g) acc[g] = (f32x4){0.f, 0.f, 0.f, 0.f};

    const u16* bb = (const u16*)Bs + lane * 8;
#pragma unroll
    for (int g = 0; g < 8; ++g) {
        bf16x8 b0 = *(const bf16x8*)(bb + (0 * 8 + g) * 512);
        acc[g] = __builtin_amdgcn_mfma_f32_16x16x32_bf16(a0, b0, acc[g], 0, 0, 0);
        bf16x8 b1 = *(const bf16x8*)(bb + (1 * 8 + g) * 512);
        acc[g] = __builtin_amdgcn_mfma_f32_16x16x32_bf16(a1, b1, acc[g], 0, 0, 0);
        bf16x8 b2 = *(const bf16x8*)(bb + (2 * 8 + g) * 512);
        acc[g] = __builtin_amdgcn_mfma_f32_16x16x32_bf16(a2, b2, acc[g], 0, 0, 0);
        bf16x8 b3 = *(const bf16x8*)(bb + (3 * 8 + g) * 512);
        acc[g] = __builtin_amdgcn_mfma_f32_16x16x32_bf16(a3, b3, acc[g], 0, 0, 0);
    }

    // epilogue: D mapping row = quad*4 + q, col = g*16 + l15
#pragma unroll
    for (int g = 0; g < 8; ++g) {
        const int col = ct * 128 + g * 16 + l15;
#pragma unroll
        for (int q = 0; q < 4; ++q) {
            const int row = n0 + wave * 16 + quad * 4 + q;
            if (row < NN)
                y[(size_t)row * KO + col] = f2bf(acc[g][q]);
        }
    }
}

// ---- aggregate: out[n] = relu( sum_e scale*y[src_e, r_e*128..] + y[n,1024..] + b )
// One wave per node; per-edge precomputed offsets broadcast via shfl; 2-wide
// batched gathers for MLP.
template <bool OUTBF>
__global__ __launch_bounds__(256) void agg_kernel(const u32* __restrict__ yv,
                                                  const int* __restrict__ off,
                                                  const u32* __restrict__ epos,
                                                  const float* __restrict__ scale,
                                                  const float* __restrict__ bias,
                                                  void* __restrict__ outp) {
    const int n = blockIdx.x * 4 + (threadIdx.x >> 6);
    const int lane = threadIdx.x & 63;
    const int e0 = off[n * 8], e1 = off[n * 8 + 8];

    float ax = 0.f, ay = 0.f;
    int cbase = e0;
    u32 ed = 0; float sc = 0.f;
    if (cbase + lane < e1) { ed = epos[cbase + lane]; sc = scale[cbase + lane]; }

    int i = e0;
    while (i < e1) {
        const int chunk_end = (e1 < cbase + 64) ? e1 : (cbase + 64);
        for (; i + 1 < chunk_end; i += 2) {
            const int j0 = i - cbase;
            const u32 p0 = (u32)__shfl((int)ed, j0);
            const u32 p1 = (u32)__shfl((int)ed, j0 + 1);
            const float f0 = __shfl(sc, j0);
            const float f1 = __shfl(sc, j0 + 1);
            const u32 v0 = yv[(size_t)p0 + lane];
            const u32 v1 = yv[(size_t)p1 + lane];
            ax += f0 * bf2f((u16)(v0 & 0xFFFFu));
            ay += f0 * bf2f((u16)(v0 >> 16));
            ax += f1 * bf2f((u16)(v1 & 0xFFFFu));
            ay += f1 * bf2f((u16)(v1 >> 16));
        }
        if (i < chunk_end) {
            const int j0 = i - cbase;
            const u32 p0 = (u32)__shfl((int)ed, j0);
            const float f0 = __shfl(sc, j0);
            const u32 v0 = yv[(size_t)p0 + lane];
            ax += f0 * bf2f((u16)(v0 & 0xFFFFu));
            ay += f0 * bf2f((u16)(v0 >> 16));
            ++i;
        }
        if (i < e1) {  // move to next chunk of 64 edges (rare)
            cbase += 64;
            const bool ok = (cbase + lane < e1);
            ed = ok ? epos[cbase + lane] : 0;
            sc = ok ? scale[cbase + lane] : 0.f;
        }
    }

    // root term + bias + relu
    const u32 rv = yv[(size_t)n * (KO / 2) + (R * D / 2) + lane];
    const float2 bb = ((const float2*)bias)[lane];
    const float ox = fmaxf(ax + bf2f((u16)(rv & 0xFFFFu)) + bb.x, 0.f);
    const float oy = fmaxf(ay + bf2f((u16)(rv >> 16)) + bb.y, 0.f);
    if (OUTBF)
        ((u32*)outp)[(size_t)n * 64 + lane] = (u32)f2bf(ox) | ((u32)f2bf(oy) << 16);
    else
        ((float2*)outp)[(size_t)n * 64 + lane] = make_float2(ox, oy);
}

extern "C" void kernel_launch(void* const* d_in, const int* in_sizes, int n_in,
                              void* d_out, int out_size, void* d_ws, size_t ws_size,
                              hipStream_t stream) {
    const float* x = (const float*)d_in[0];
    const int* ei = (const int*)d_in[1];
    const int* et = (const int*)d_in[2];
    const float* w1 = (const float*)d_in[3];
    const float* root1 = (const float*)d_in[4];
    const float* b1 = (const float*)d_in[5];
    const float* w2 = (const float*)d_in[6];
    const float* root2 = (const float*)d_in[7];
    const float* b2 = (const float*)d_in[8];
    float* out = (float*)d_out;

    char* ws = (char*)d_ws;
    int* off    = (int*)(ws + 0);                  // (NR+1) ints
    int* cnt_i  = (int*)(ws + 1600512);            // NR ints
    int* cursor = (int*)(ws + 3200512);            // NR ints
    int* bsum   = (int*)(ws + 4800512);
    int* boff   = (int*)(ws + 4802304);
    u32* epos   = (u32*)(ws + 4804096);            // EE u32 (2.4 MB)
    float* scl  = (float*)(ws + 7204096);          // EE f32 (2.4 MB)
    u32* xb     = (u32*)(ws + 9604096);            // N*D bf16 = 12.8 MB
    u32* h      = (u32*)(ws + 22404096);           // N*D bf16 = 12.8 MB
    u16* y      = (u16*)(ws + 35204096);           // N*1152 bf16 = 115.2 MB
    u16* Bf1    = (u16*)(ws + 150404096);          // 294912 B
    u16* Bf2    = (u16*)(ws + 150699008);          // 294912 B

    const int* srcp = ei;
    const int* dstp = ei + EE;

    // ---- input cast + CSR build (shared by both layers) ----
    xcast_kernel<<<(NN * D / 2 + 255) / 256, 256, 0, stream>>>((const float2*)x,
                                                               xb, NN * D / 2);
    hipMemsetAsync(cnt_i, 0, (size_t)NR * sizeof(int), stream);
    hist_kernel<<<(EE + 255) / 256, 256, 0, stream>>>(dstp, et, cnt_i, EE);
    scanA<<<NSB, 256, 0, stream>>>(cnt_i, off, bsum);
    scanB<<<1, 512, 0, stream>>>(bsum, boff);
    scanC<<<NSB, 256, 0, stream>>>(off, cursor, boff);
    place_kernel<<<(EE + 255) / 256, 256, 0, stream>>>(srcp, dstp, et, cnt_i,
                                                       cursor, epos, scl, EE);
    bprep2_kernel<<<(2 * 9 * 4 * 8 * 64 + 255) / 256, 256, 0, stream>>>(
        w1, root1, Bf1, w2, root2, Bf2);

    const dim3 ggrid((NN + 63) / 64, 9);      // 782 x 9
    const int agg_blocks = NN / 4;            // 12500

    // layer 1: xb -> y -> h (bf16)
    gemm_xw<<<ggrid, 256, 0, stream>>>((const u16*)xb, Bf1, y);
    agg_kernel<true><<<agg_blocks, 256, 0, stream>>>((const u32*)y, off, epos,
                                                     scl, b1, h);

    // layer 2: h -> y -> out (fp32)
    gemm_xw<<<ggrid, 256, 0, stream>>>((const u16*)h, Bf2, y);
    agg_kernel<false><<<agg_blocks, 256, 0, stream>>>((const u32*)y, off, epos,
                                                      scl, b2, out);
}